// Round 1
// baseline (831.657 us; speedup 1.0000x reference)
//
#include <hip/hip_runtime.h>
#include <math.h>

// GridLSTM one-flag-per-cell dataflow, fused f16 weights. V=50000,E=300,H=128,L=32,B=8.
// 256 blocks x 256 threads. bid = c*32 + i (i = grid row, c = t-slice chunk 0..7).
// Key identity: h_in = [W_ch@ho_up + b_ch ; W_ch@ho_left + b_ch]  =>
//   gates = WU@ho_up + WL@ho_left + (Pproj+b) + Hypproj + upok*bU + lfok*bL
// with WU = W_hh[:,:128]@W_ch, WL = W_hh[:,128:]@W_ch (precomputed on device,
// packed f16x2, consumed via v_dot2_f32_f16 -> 128 VGPRs of weights/thread).
//
// R1 change (sync restructure): seqlock tags embedded in the data.
//   Ho published as u64 = (tag<<32)|f16x2 pair (same cvt_pkrtz as the old
//   consumer-side conversion -> bit-identical GEMM inputs).
//   Co published as u64 = (tag<<32)|f32.  tag = i*32+j+1, unique per depth-4
//   ring generation, never equals the 0xAAAAAAAA ws poison.
//   Producer: tagged stores only - NO vmcnt drain, NO publish barrier; tid0
//   stores the old flag as an ADVISORY coarse signal (correctness lives in tags).
//   Consumer: 1 optimistic tagged sweep (steady-state hit = single UC round
//   trip, collapsing flag-detect + data-load); __syncthreads_or fallback to
//   the cheap advisory-flag spin (throttles idle-row poll traffic), re-sweep.
//   Final corner ho(31,31) gets a dedicated (tag<<32)|f32 buffer for the MLP.

typedef _Float16 h2 __attribute__((ext_vector_type(2)));

__device__ __forceinline__ h2 pk_f16(float a, float b) {
    return __builtin_bit_cast(h2, __builtin_amdgcn_cvt_pkrtz(a, b));
}

// ---------------- workspace layout (float words) ----------------
#define HYP_OFF   0            // Hypproj [32 j][8 b][1024]            (atomic f32)
#define WP_OFF    262144       // fused wts packed h2 [1024 g][256]    (atomic u32)
#define B_OFF     524288       // bU[1024] | bL[1024]
#define INITF_OFF 526336       // InitF [p*16] (4096)
#define HF_OFF    530432       // advisory HF [(i*8+c)*16] (4096)
#define HOT_OFF   534528       // Ho tagged u64 [4 dep][32 j][8 b][128 kk]  (1 MB)
#define COT_OFF   796672       // Co tagged u64 [4 dep][32 j][8 b][256 t]   (2 MB)
#define HOF_OFF   1320960      // final ho(31,31) tagged u64 [8 b][256 t]   (16 KB)
// end = 1325056 floats = 5.30 MB of ws

#define BASE 0xAAAAAAAAu

__device__ __forceinline__ float sigm(float x) { return 1.f / (1.f + __expf(-x)); }
__device__ __forceinline__ float tanh_fast(float x) { return 1.f - 2.f / (__expf(2.f * x) + 1.f); }

__device__ __forceinline__ unsigned ld_flag(const unsigned* p) {
    return __hip_atomic_load(p, __ATOMIC_RELAXED, __HIP_MEMORY_SCOPE_AGENT);
}
__device__ __forceinline__ void st_flag(unsigned* p, unsigned v) {
    __hip_atomic_store(p, v, __ATOMIC_RELAXED, __HIP_MEMORY_SCOPE_AGENT);
}
__device__ __forceinline__ float ld_f32(const float* p) {
    unsigned u = __hip_atomic_load((const unsigned*)p, __ATOMIC_RELAXED, __HIP_MEMORY_SCOPE_AGENT);
    return __uint_as_float(u);
}
__device__ __forceinline__ void st_f32(float* p, float v) {
    __hip_atomic_store((unsigned*)p, __float_as_uint(v), __ATOMIC_RELAXED, __HIP_MEMORY_SCOPE_AGENT);
}
__device__ __forceinline__ void st_u32(unsigned* p, unsigned v) {
    __hip_atomic_store(p, v, __ATOMIC_RELAXED, __HIP_MEMORY_SCOPE_AGENT);
}
__device__ __forceinline__ unsigned long long ld_u64(const unsigned long long* p) {
    return __hip_atomic_load(p, __ATOMIC_RELAXED, __HIP_MEMORY_SCOPE_AGENT);
}
__device__ __forceinline__ void st_u64(unsigned long long* p, unsigned long long v) {
    __hip_atomic_store(p, v, __ATOMIC_RELAXED, __HIP_MEMORY_SCOPE_AGENT);
}
__device__ __forceinline__ void wait_ge(const unsigned* f, unsigned target) {
    long spins = 0;
    while ((ld_flag(f) - BASE) < target) {
        __builtin_amdgcn_s_sleep(1);
        if (++spins > (1L << 22)) break;   // failsafe: wrong answer > hang
    }
}
__device__ __forceinline__ void drain_vmem() {
    asm volatile("s_waitcnt vmcnt(0)" ::: "memory");
}

// one tagged sweep over this thread's 16 dependency slots (predicated on pend)
#define SWEEP_ONCE() do {                                                              \
    _Pragma("unroll")                                                                  \
    for (int r_ = 0; r_ < 4; r_++) {                                                   \
        const int idx_ = r_ * 256 + tid;                                               \
        const int b_ = idx_ >> 7, kk_ = idx_ & 127;                                    \
        if (pend & (1u << r_))      uv[r_]  = ld_u64(HoUpT + b_ * 128 + kk_);          \
        if (pend & (0x10u << r_))   lv[r_]  = ld_u64(HoLfT + b_ * 128 + kk_);          \
        if (pend & (0x100u << r_))  c0v[r_] = ld_u64(CoST + b_ * 256 + 2 * kk_);       \
        if (pend & (0x1000u << r_)) c1v[r_] = ld_u64(CoST + b_ * 256 + 2 * kk_ + 1);   \
    }                                                                                  \
    _Pragma("unroll")                                                                  \
    for (int r_ = 0; r_ < 4; r_++) {                                                   \
        if ((pend & (1u << r_))      && (unsigned)(uv[r_] >> 32)  == upTag) pend &= ~(1u << r_);      \
        if ((pend & (0x10u << r_))   && (unsigned)(lv[r_] >> 32)  == lfTag) pend &= ~(0x10u << r_);   \
        if ((pend & (0x100u << r_))  && (unsigned)(c0v[r_] >> 32) == coTag) pend &= ~(0x100u << r_);  \
        if ((pend & (0x1000u << r_)) && (unsigned)(c1v[r_] >> 32) == coTag) pend &= ~(0x1000u << r_); \
    }                                                                                  \
} while (0)

__global__ void __launch_bounds__(256, 1) grid_lstm_kernel(
    const int* __restrict__ premise, const int* __restrict__ hypothesis,
    const float* __restrict__ emb,
    const float* __restrict__ W_ih, const float* __restrict__ b_ih,
    const float* __restrict__ W_hh, const float* __restrict__ b_hh,
    const float* __restrict__ W_ch, const float* __restrict__ b_ch,
    const float* __restrict__ W_cc, const float* __restrict__ b_cc,
    const float* __restrict__ W1, const float* __restrict__ b1,
    const float* __restrict__ W2, const float* __restrict__ b2,
    const float* __restrict__ W3, const float* __restrict__ b3,
    float* __restrict__ out, float* __restrict__ ws)
{
    __shared__ h2    hAB[2048];      // f16 [8 b][256 kk]: kk<128 up, kk>=128 left (8KB)
    __shared__ float sCo[2048];      // f32 co_side [8 b][256] (8KB)
    __shared__ float ppL[1024];      // Pproj slice [8 b][128 g], g=(a<<5)|s (4KB)
    __shared__ float red[8448];      // gate partials [256][33] / embs / MLP (33.8KB)
    __shared__ float red2[2304];     // c partials [256][9] (9.2KB)

    const int tid = threadIdx.x;
    const int bid = blockIdx.x;
    const int i   = bid & 31;       // grid row
    const int c   = bid >> 5;       // t-slice chunk

    float*              Hypproj = ws + HYP_OFF;
    unsigned*           WP      = (unsigned*)(ws + WP_OFF);
    float*              BU      = ws + B_OFF;
    float*              BL      = ws + B_OFF + 1024;
    unsigned*           InitF   = (unsigned*)(ws + INITF_OFF);   // [p*16]
    unsigned*           HF      = (unsigned*)(ws + HF_OFF);      // advisory [(i*8+c)*16]
    unsigned long long* HoT     = (unsigned long long*)(ws + HOT_OFF);
    unsigned long long* CoT     = (unsigned long long*)(ws + COT_OFF);
    unsigned long long* HoF     = (unsigned long long*)(ws + HOF_OFF);

    const int tq = tid & 31, ks = tid >> 5;   // GEMM K-split coords
    const int tl = tid & 31, bb = tid >> 5;   // elementwise coords (t_local, batch)

    // ================= Init A: Pproj (LDS) + Hypproj for this block's gate rows ====
    {
        float* embs = red;   // [2 sides][8][300] = 4800 floats
        for (int idx = tid; idx < 4800; idx += 256) {
            int side = idx / 2400, rem = idx - side * 2400;
            int b = rem / 300, e = rem - b * 300;
            const int* toks = side ? hypothesis : premise;
            embs[idx] = emb[(long)toks[b * 32 + i] * 300 + e];
        }
        __syncthreads();
        #pragma unroll 1
        for (int q = 0; q < 4; q++) {
            const int oo = tid + q * 256;
            const int b = oo >> 7, g = oo & 127;
            const int gr = (g >> 5) * 256 + c * 32 + (g & 31);   // t-sliced gate row
            float accP = b_ih[gr] + b_hh[gr];
            float accH = 0.f;
            const float* wp = W_ih + (long)gr * 600;
            const float* eP = embs + b * 300;
            const float* eH = embs + 2400 + b * 300;
            for (int e = 0; e < 300; e += 4) {
                float4 w1 = *(const float4*)(wp + e);
                float4 w2v = *(const float4*)(wp + 300 + e);
                float4 p4 = *(const float4*)(eP + e);
                float4 h4 = *(const float4*)(eH + e);
                accP += w1.x * p4.x + w1.y * p4.y + w1.z * p4.z + w1.w * p4.w;
                accH += w2v.x * h4.x + w2v.y * h4.y + w2v.z * h4.z + w2v.w * h4.w;
            }
            st_f32(&Hypproj[i * 8192 + b * 1024 + gr], accH);     // cross-block
            ppL[b * 128 + g] = accP;                              // block-local
        }
        __syncthreads();   // embs (red) free
    }

    // ================= Init B: fused weight rows [4*bid, 4*bid+4) =================
    {
        const int tr = tid >> 6, col = (tid & 63) * 4;
        const int r  = bid * 4 + tr;
        float u[4] = {0.f, 0.f, 0.f, 0.f}, l[4] = {0.f, 0.f, 0.f, 0.f};
        const float* whU = W_hh + (long)r * 256;
        const float* whL = whU + 128;
        for (int k = 0; k < 128; k++) {
            const float wu = whU[k], wl = whL[k];
            float4 wc = *(const float4*)(W_ch + (long)k * 256 + col);
            u[0] += wu * wc.x; u[1] += wu * wc.y; u[2] += wu * wc.z; u[3] += wu * wc.w;
            l[0] += wl * wc.x; l[1] += wl * wc.y; l[2] += wl * wc.z; l[3] += wl * wc.w;
        }
        unsigned* wrow = WP + (long)r * 256;
        st_u32(&wrow[col / 2],       __builtin_bit_cast(unsigned, __builtin_amdgcn_cvt_pkrtz(u[0], u[1])));
        st_u32(&wrow[col / 2 + 1],   __builtin_bit_cast(unsigned, __builtin_amdgcn_cvt_pkrtz(u[2], u[3])));
        st_u32(&wrow[128 + col / 2],     __builtin_bit_cast(unsigned, __builtin_amdgcn_cvt_pkrtz(l[0], l[1])));
        st_u32(&wrow[128 + col / 2 + 1], __builtin_bit_cast(unsigned, __builtin_amdgcn_cvt_pkrtz(l[2], l[3])));
        if ((tid & 63) == 0) {   // bias projections for this row
            float su = 0.f, sl = 0.f;
            for (int k = 0; k < 128; k++) { su += whU[k] * b_ch[k]; sl += whL[k] * b_ch[k]; }
            st_f32(&BU[r], su); st_f32(&BL[r], sl);
        }
    }
    drain_vmem();
    __syncthreads();
    if (tid == 0) st_flag(&InitF[bid * 16], BASE + 1u);

    // ---- wait ALL inits (covers every Hypproj row + all fused weights) ----
    wait_ge(&InitF[tid * 16], 1u);
    __syncthreads();

    // ---- load fused weight slice -> registers (f16x2), W_cc slice (fp32) ----
    h2 w[4][32];                  // 128 VGPRs
    #pragma unroll
    for (int a = 0; a < 4; a++) {
        const unsigned* src = WP + (long)(a * 256 + c * 32 + tq) * 256 + ks * 32;
        #pragma unroll
        for (int m = 0; m < 16; m++) {
            unsigned long long u2 = ld_u64((const unsigned long long*)(src + m * 2));
            w[a][2 * m]     = __builtin_bit_cast(h2, (unsigned)u2);
            w[a][2 * m + 1] = __builtin_bit_cast(h2, (unsigned)(u2 >> 32));
        }
    }
    float4 w3[8];                 // 32 VGPRs: W_cc row (c&3)*32+tq, K-seg ks*32..+32
    {
        const float* wr = W_cc + (long)((c & 3) * 32 + tq) * 256 + ks * 32;
        #pragma unroll
        for (int m = 0; m < 8; m++) w3[m] = *(const float4*)(wr + m * 4);
    }
    float bUv[4], bLv[4];
    #pragma unroll
    for (int a = 0; a < 4; a++) {
        bUv[a] = ld_f32(&BU[a * 256 + c * 32 + tl]);
        bLv[a] = ld_f32(&BL[a * 256 + c * 32 + tl]);
    }

    // ================= Wavefront: row i walks j = 0..31 =================
    #pragma unroll 1
    for (int j = 0; j < 32; j++) {
        const bool upok = (i > 0), lfok = (j > 0);
        const bool cok  = (c < 4) ? upok : lfok;
        const int  jl   = lfok ? (j - 1) : 0;

        const unsigned upTag = (unsigned)((i - 1) * 32 + j + 1);   // tag of cell (i-1,j)
        const unsigned lfTag = (unsigned)(i * 32 + j);             // tag of cell (i,j-1)
        const unsigned coTag = (c < 4) ? upTag : lfTag;

        const unsigned long long* HoUpT = HoT + (size_t)(((i - 1) & 3) * 32 + j) * 1024;
        const unsigned long long* HoLfT = HoT + (size_t)((i & 3) * 32 + jl) * 1024;
        const unsigned long long* CoST  = (c < 4)
            ? CoT + (size_t)(((i - 1) & 3) * 32 + j) * 2048
            : CoT + (size_t)((i & 3) * 32 + jl) * 2048;

        // ---- prefetch Hypproj for elementwise (independent, overlaps the sweep) ----
        float hyv[4];
        #pragma unroll
        for (int a = 0; a < 4; a++)
            hyv[a] = ld_f32(&Hypproj[j * 8192 + bb * 1024 + a * 256 + c * 32 + tl]);

        // ---- tagged dependency acquire ----
        unsigned long long uv[4], lv[4], c0v[4], c1v[4];
        unsigned pend = (upok ? 0x000Fu : 0u) | (lfok ? 0x00F0u : 0u) | (cok ? 0xFF00u : 0u);

        SWEEP_ONCE();   // optimistic: steady-state wavefront usually hits here

        if (__syncthreads_or((int)(pend != 0u))) {
            // coarse advisory wait (throttles idle-row poll traffic)
            if (upok && tid < 8)              wait_ge(&HF[((i - 1) * 8 + tid) * 16], (unsigned)(j + 1));
            if (lfok && tid >= 8 && tid < 16) wait_ge(&HF[(i * 8 + (tid - 8)) * 16], (unsigned)j);
            __syncthreads();
            long spins = 0;
            while (pend) {
                SWEEP_ONCE();
                if (pend) {
                    __builtin_amdgcn_s_sleep(1);
                    if (++spins > (1L << 20)) break;   // failsafe: wrong answer > hang
                }
            }
        }

        // ---- stage into LDS: h (f16 pairs) and co_side (f32) ----
        #pragma unroll
        for (int r = 0; r < 4; r++) {
            const int idx = r * 256 + tid;
            const int b = idx >> 7, kk = idx & 127;
            hAB[b * 256 + kk]       = upok ? __builtin_bit_cast(h2, (unsigned)uv[r]) : pk_f16(0.f, 0.f);
            hAB[b * 256 + 128 + kk] = lfok ? __builtin_bit_cast(h2, (unsigned)lv[r]) : pk_f16(0.f, 0.f);
            sCo[b * 256 + 2 * kk]     = cok ? __uint_as_float((unsigned)c0v[r]) : 0.f;
            sCo[b * 256 + 2 * kk + 1] = cok ? __uint_as_float((unsigned)c1v[r]) : 0.f;
        }
        __syncthreads();

        // ---- fused gates GEMM (f16 dot2) + c-path (fp32) ----
        float acc[4][8], a3[8];
        #pragma unroll
        for (int a = 0; a < 4; a++)
            #pragma unroll
            for (int b = 0; b < 8; b++) acc[a][b] = 0.f;
        #pragma unroll
        for (int b = 0; b < 8; b++) a3[b] = 0.f;
        #pragma unroll
        for (int b = 0; b < 8; b++) {
            const h2*    hb = hAB + b * 256 + ks * 32;
            const float* cb = sCo + b * 256 + ks * 32;
            #pragma unroll
            for (int m4 = 0; m4 < 8; m4++) {
                uint4 hu = *(const uint4*)(hb + m4 * 4);
                h2 h0 = __builtin_bit_cast(h2, hu.x);
                h2 h1 = __builtin_bit_cast(h2, hu.y);
                h2 h2v = __builtin_bit_cast(h2, hu.z);
                h2 h3 = __builtin_bit_cast(h2, hu.w);
                #pragma unroll
                for (int a = 0; a < 4; a++) {
                    acc[a][b] = __builtin_amdgcn_fdot2(w[a][m4 * 4],     h0,  acc[a][b], false);
                    acc[a][b] = __builtin_amdgcn_fdot2(w[a][m4 * 4 + 1], h1,  acc[a][b], false);
                    acc[a][b] = __builtin_amdgcn_fdot2(w[a][m4 * 4 + 2], h2v, acc[a][b], false);
                    acc[a][b] = __builtin_amdgcn_fdot2(w[a][m4 * 4 + 3], h3,  acc[a][b], false);
                }
                float4 cv = *(const float4*)(cb + m4 * 4);
                a3[b] += w3[m4].x * cv.x + w3[m4].y * cv.y + w3[m4].z * cv.z + w3[m4].w * cv.w;
            }
        }
        #pragma unroll
        for (int a = 0; a < 4; a++)
            #pragma unroll
            for (int b = 0; b < 8; b++) red[tid * 33 + a * 8 + b] = acc[a][b];
        #pragma unroll
        for (int b = 0; b < 8; b++) red2[tid * 9 + b] = a3[b];
        __syncthreads();

        // ---- elementwise (block-local) + tagged publish of h_o/c_o slice ----
        {
            float g4[4];
            #pragma unroll
            for (int a = 0; a < 4; a++) {
                float s = 0.f;
                #pragma unroll
                for (int k = 0; k < 8; k++)
                    s += red[(k * 32 + tl) * 33 + a * 8 + bb];
                s += ppL[bb * 128 + a * 32 + tl] + hyv[a];
                if (upok) s += bUv[a];
                if (lfok) s += bLv[a];
                g4[a] = s;
            }
            float ci = 0.f;
            #pragma unroll
            for (int k = 0; k < 8; k++) ci += red2[(k * 32 + tl) * 9 + bb];
            if (cok) ci += b_cc[(c & 3) * 32 + tl];
            const float cnew = sigm(g4[1]) * ci + sigm(g4[0]) * tanh_fast(g4[2]);
            const float hnew = sigm(g4[3]) * tanh_fast(cnew);

            const unsigned myTag = (unsigned)(i * 32 + j + 1);
            const unsigned long long tagHi = ((unsigned long long)myTag) << 32;
            const int slot = (i & 3) * 32 + j;

            // Co: every thread publishes its (b, t) f32 with tag
            st_u64(&CoT[(size_t)slot * 2048 + bb * 256 + c * 32 + tl],
                   tagHi | (unsigned long long)__float_as_uint(cnew));
            // Ho: even lanes publish the (t, t+1) f16 pair with tag
            const float hOdd = __shfl_xor(hnew, 1);
            if ((tl & 1) == 0) {
                const h2 pr = pk_f16(hnew, hOdd);
                st_u64(&HoT[(size_t)slot * 1024 + bb * 128 + c * 16 + (tl >> 1)],
                       tagHi | (unsigned long long)__builtin_bit_cast(unsigned, pr));
            }
            // corner cell: full-precision ho for the final MLP
            if (i == 31 && j == 31)
                st_u64(&HoF[bb * 256 + c * 32 + tl],
                       tagHi | (unsigned long long)__float_as_uint(hnew));
        }
        // advisory flag: no drain, no barrier (tags carry correctness)
        if (tid == 0) st_flag(&HF[(i * 8 + c) * 16], BASE + (unsigned)(j + 1));
    }

    // ================= Final: condense ho(31,31) + MLP + softmax (bid 31) ==========
    if (bid == 31) {
        const unsigned fTag = 1024u;   // 31*32 + 31 + 1
        float hov[8] = {0.f, 0.f, 0.f, 0.f, 0.f, 0.f, 0.f, 0.f};
        unsigned pf = 0xFFu;
        long spins = 0;
        while (pf) {
            unsigned long long tv[8];
            #pragma unroll
            for (int r = 0; r < 8; r++)
                if (pf & (1u << r)) tv[r] = ld_u64(HoF + r * 256 + tid);
            #pragma unroll
            for (int r = 0; r < 8; r++)
                if ((pf & (1u << r)) && (unsigned)(tv[r] >> 32) == fTag) {
                    hov[r] = __uint_as_float((unsigned)tv[r]);
                    pf &= ~(1u << r);
                }
            if (pf) {
                __builtin_amdgcn_s_sleep(1);
                if (++spins > (1L << 22)) break;   // failsafe
            }
        }
        #pragma unroll
        for (int r = 0; r < 8; r++) sCo[r * 256 + tid] = hov[r];
        __syncthreads();
        // condense: hcond[b][o] = b_ch[o] + W_ch[o,:] @ ho[b,:]
        #pragma unroll 1
        for (int q = 0; q < 4; q++) {
            const int oo = tid + q * 256;
            const int b = oo >> 7, o = oo & 127;
            float a = b_ch[o];
            const float* wr = W_ch + (long)o * 256;
            const float* x = sCo + b * 256;
            for (int k = 0; k < 256; k += 4) {
                float4 wv = *(const float4*)(wr + k);
                float4 xv = *(const float4*)(x + k);
                a += wv.x * xv.x + wv.y * xv.y + wv.z * xv.z + wv.w * xv.w;
            }
            ppL[b * 128 + o] = a;
        }
        __syncthreads();
        float* m1 = red;          // [8][128]
        float* m2 = red + 1024;   // [8][128]
        for (int idx = tid; idx < 1024; idx += 256) {
            int b = idx >> 7, o = idx & 127;
            float a = b1[o];
            const float* wr = W1 + o * 128; const float* x = ppL + b * 128;
            for (int k = 0; k < 128; k++) a += wr[k] * x[k];
            m1[idx] = fmaxf(a, 0.f);
        }
        __syncthreads();
        for (int idx = tid; idx < 1024; idx += 256) {
            int b = idx >> 7, o = idx & 127;
            float a = b2[o];
            const float* wr = W2 + o * 128; const float* x = m1 + b * 128;
            for (int k = 0; k < 128; k++) a += wr[k] * x[k];
            m2[idx] = fmaxf(a, 0.f);
        }
        __syncthreads();
        if (tid < 8) {
            const int b = tid;
            float lg[3];
            for (int cc = 0; cc < 3; cc++) {
                float a = b3[cc];
                const float* wr = W3 + cc * 128; const float* x = m2 + b * 128;
                for (int k = 0; k < 128; k++) a += wr[k] * x[k];
                lg[cc] = a;
            }
            float m = fmaxf(lg[0], fmaxf(lg[1], lg[2]));
            float e0 = expf(lg[0] - m), e1 = expf(lg[1] - m), e2 = expf(lg[2] - m);
            float s = e0 + e1 + e2;
            out[b * 3 + 0] = e0 / s;
            out[b * 3 + 1] = e1 / s;
            out[b * 3 + 2] = e2 / s;
        }
    }
}

extern "C" void kernel_launch(void* const* d_in, const int* in_sizes, int n_in,
                              void* d_out, int out_size, void* d_ws, size_t ws_size,
                              hipStream_t stream) {
    const int*   premise    = (const int*)d_in[0];
    const int*   hypothesis = (const int*)d_in[1];
    const float* emb        = (const float*)d_in[2];
    const float* W_ih       = (const float*)d_in[3];
    const float* b_ih       = (const float*)d_in[4];
    const float* W_hh       = (const float*)d_in[5];
    const float* b_hh       = (const float*)d_in[6];
    const float* W_ch       = (const float*)d_in[7];
    const float* b_ch       = (const float*)d_in[8];
    const float* W_cc       = (const float*)d_in[9];
    const float* b_cc       = (const float*)d_in[10];
    const float* W1         = (const float*)d_in[11];
    const float* b1         = (const float*)d_in[12];
    const float* W2         = (const float*)d_in[13];
    const float* b2         = (const float*)d_in[14];
    const float* W3         = (const float*)d_in[15];
    const float* b3         = (const float*)d_in[16];
    float* out = (float*)d_out;
    float* ws  = (float*)d_ws;

    (void)in_sizes; (void)n_in; (void)out_size; (void)ws_size;

    grid_lstm_kernel<<<dim3(256), dim3(256), 0, stream>>>(
        premise, hypothesis, emb, W_ih, b_ih, W_hh, b_hh,
        W_ch, b_ch, W_cc, b_cc, W1, b1, W2, b2, W3, b3, out, ws);
}

// Round 2
// 795.339 us; speedup vs baseline: 1.0457x; 1.0457x over previous
//
#include <hip/hip_runtime.h>
#include <math.h>

// GridLSTM one-flag-per-cell dataflow, fused f16 weights. V=50000,E=300,H=128,L=32,B=8.
// 256 blocks x 256 threads. bid = c*32 + i (i = grid row, c = t-slice chunk 0..7).
// Key identity: h_in = [W_ch@ho_up + b_ch ; W_ch@ho_left + b_ch]  =>
//   gates = WU@ho_up + WL@ho_left + (Pproj+b) + Hypproj + upok*bU + lfok*bL
// with WU = W_hh[:,:128]@W_ch, WL = W_hh[:,128:]@W_ch (precomputed on device,
// packed f16x2, consumed via v_dot2_f32_f16 -> 128 VGPRs of weights/thread).
//
// R2 sync design (post-mortem of R1's null result): fine-grained PER-WAVE flags.
//   Producer: each wave UC-stores its Ho/Co slice, drains its OWN stores
//   (s_waitcnt vmcnt(0) is wave-local), lane0-of-wave stores WF[blk][wave]=j+1.
//   No producer __syncthreads, no tags. Flag-visible => that wave's data visible.
//   Consumer: 60 lanes of wave0 spin on 60 tiny flag words (8 up-blocks x4
//   waves + 7 left-siblings x4 waves) in ONE combined divergent loop (up and
//   left wait concurrently; lanes exit individually). Then ONE bulk load, no
//   retries. Ho travels as producer-packed f16x2 (bit-identical cvt_pkrtz,
//   half the bytes). All inter-block data loads stay agent-scope (L2 bypass:
//   rows i and i+8 share an XCD and reuse ring addresses -> L2 would be stale).

typedef _Float16 h2 __attribute__((ext_vector_type(2)));

__device__ __forceinline__ h2 pk_f16(float a, float b) {
    return __builtin_bit_cast(h2, __builtin_amdgcn_cvt_pkrtz(a, b));
}

// ---------------- workspace layout (float words) ----------------
#define HYP_OFF   0            // Hypproj [32 j][8 b][1024]            (atomic f32)
#define WP_OFF    262144       // fused wts packed h2 [1024 g][256]    (atomic u32)
#define B_OFF     524288       // bU[1024] | bL[1024]
#define INITF_OFF 526336       // InitF [p*16] (4096)
#define WF_OFF    530432       // per-wave flags [(i*8+c)*4 + w]*16 (16384)
#define HO_OFF    546816       // Ho f16x2 u32 [4 dep][32 j][8 b][128 kk] (512KB)
#define CO_OFF    677888       // Co f32 [4 dep][32 j][8 b][256 t]        (1MB)
#define HOF_OFF   940032       // final ho(31,31) f32 [8 b][256 t]        (8KB)
// end = 942080 floats = 3.77 MB of ws

#define BASE 0xAAAAAAAAu

__device__ __forceinline__ float sigm(float x) { return 1.f / (1.f + __expf(-x)); }
__device__ __forceinline__ float tanh_fast(float x) { return 1.f - 2.f / (__expf(2.f * x) + 1.f); }

__device__ __forceinline__ unsigned ld_flag(const unsigned* p) {
    return __hip_atomic_load(p, __ATOMIC_RELAXED, __HIP_MEMORY_SCOPE_AGENT);
}
__device__ __forceinline__ void st_flag(unsigned* p, unsigned v) {
    __hip_atomic_store(p, v, __ATOMIC_RELAXED, __HIP_MEMORY_SCOPE_AGENT);
}
__device__ __forceinline__ float ld_f32(const float* p) {
    unsigned u = __hip_atomic_load((const unsigned*)p, __ATOMIC_RELAXED, __HIP_MEMORY_SCOPE_AGENT);
    return __uint_as_float(u);
}
__device__ __forceinline__ void st_f32(float* p, float v) {
    __hip_atomic_store((unsigned*)p, __float_as_uint(v), __ATOMIC_RELAXED, __HIP_MEMORY_SCOPE_AGENT);
}
__device__ __forceinline__ void st_u32(unsigned* p, unsigned v) {
    __hip_atomic_store(p, v, __ATOMIC_RELAXED, __HIP_MEMORY_SCOPE_AGENT);
}
__device__ __forceinline__ unsigned long long ld_u64(const unsigned long long* p) {
    return __hip_atomic_load(p, __ATOMIC_RELAXED, __HIP_MEMORY_SCOPE_AGENT);
}
__device__ __forceinline__ float2 ld_f32x2(const float* p) {   // 8B-aligned
    unsigned long long u = ld_u64((const unsigned long long*)p);
    float2 r; r.x = __uint_as_float((unsigned)u); r.y = __uint_as_float((unsigned)(u >> 32));
    return r;
}
__device__ __forceinline__ void wait_ge(const unsigned* f, unsigned target) {
    long spins = 0;
    while ((ld_flag(f) - BASE) < target) {
        __builtin_amdgcn_s_sleep(1);
        if (++spins > (1L << 22)) break;   // failsafe: wrong answer > hang
    }
}
__device__ __forceinline__ void drain_vmem() {
    asm volatile("s_waitcnt vmcnt(0)" ::: "memory");
}

__global__ void __launch_bounds__(256, 1) grid_lstm_kernel(
    const int* __restrict__ premise, const int* __restrict__ hypothesis,
    const float* __restrict__ emb,
    const float* __restrict__ W_ih, const float* __restrict__ b_ih,
    const float* __restrict__ W_hh, const float* __restrict__ b_hh,
    const float* __restrict__ W_ch, const float* __restrict__ b_ch,
    const float* __restrict__ W_cc, const float* __restrict__ b_cc,
    const float* __restrict__ W1, const float* __restrict__ b1,
    const float* __restrict__ W2, const float* __restrict__ b2,
    const float* __restrict__ W3, const float* __restrict__ b3,
    float* __restrict__ out, float* __restrict__ ws)
{
    __shared__ h2    hAB[2048];      // f16 [8 b][256 kk]: kk<128 up, kk>=128 left (8KB)
    __shared__ float sCo[2048];      // f32 co_side [8 b][256] (8KB)
    __shared__ float ppL[1024];      // Pproj slice [8 b][128 g], g=(a<<5)|s (4KB)
    __shared__ float red[8448];      // gate partials [256][33] / embs / MLP (33.8KB)
    __shared__ float red2[2304];     // c partials [256][9] (9.2KB)

    const int tid = threadIdx.x;
    const int bid = blockIdx.x;
    const int i   = bid & 31;       // grid row
    const int c   = bid >> 5;       // t-slice chunk

    float*    Hypproj = ws + HYP_OFF;
    unsigned* WP      = (unsigned*)(ws + WP_OFF);
    float*    BU      = ws + B_OFF;
    float*    BL      = ws + B_OFF + 1024;
    unsigned* InitF   = (unsigned*)(ws + INITF_OFF);   // [p*16]
    unsigned* WF      = (unsigned*)(ws + WF_OFF);      // [((i*8+c)*4+w)*16]
    unsigned* Ho      = (unsigned*)(ws + HO_OFF);      // f16x2 per entry
    float*    Co      = ws + CO_OFF;
    float*    HoF     = ws + HOF_OFF;

    const int tq = tid & 31, ks = tid >> 5;   // GEMM K-split coords
    const int tl = tid & 31, bb = tid >> 5;   // elementwise coords (t_local, batch)

    // ================= Init A: Pproj (LDS) + Hypproj for this block's gate rows ====
    {
        float* embs = red;   // [2 sides][8][300] = 4800 floats
        for (int idx = tid; idx < 4800; idx += 256) {
            int side = idx / 2400, rem = idx - side * 2400;
            int b = rem / 300, e = rem - b * 300;
            const int* toks = side ? hypothesis : premise;
            embs[idx] = emb[(long)toks[b * 32 + i] * 300 + e];
        }
        __syncthreads();
        #pragma unroll 1
        for (int q = 0; q < 4; q++) {
            const int oo = tid + q * 256;
            const int b = oo >> 7, g = oo & 127;
            const int gr = (g >> 5) * 256 + c * 32 + (g & 31);   // t-sliced gate row
            float accP = b_ih[gr] + b_hh[gr];
            float accH = 0.f;
            const float* wp = W_ih + (long)gr * 600;
            const float* eP = embs + b * 300;
            const float* eH = embs + 2400 + b * 300;
            for (int e = 0; e < 300; e += 4) {
                float4 w1 = *(const float4*)(wp + e);
                float4 w2v = *(const float4*)(wp + 300 + e);
                float4 p4 = *(const float4*)(eP + e);
                float4 h4 = *(const float4*)(eH + e);
                accP += w1.x * p4.x + w1.y * p4.y + w1.z * p4.z + w1.w * p4.w;
                accH += w2v.x * h4.x + w2v.y * h4.y + w2v.z * h4.z + w2v.w * h4.w;
            }
            st_f32(&Hypproj[i * 8192 + b * 1024 + gr], accH);     // cross-block
            ppL[b * 128 + g] = accP;                              // block-local
        }
        __syncthreads();   // embs (red) free
    }

    // ================= Init B: fused weight rows [4*bid, 4*bid+4) =================
    {
        const int tr = tid >> 6, col = (tid & 63) * 4;
        const int r  = bid * 4 + tr;
        float u[4] = {0.f, 0.f, 0.f, 0.f}, l[4] = {0.f, 0.f, 0.f, 0.f};
        const float* whU = W_hh + (long)r * 256;
        const float* whL = whU + 128;
        for (int k = 0; k < 128; k++) {
            const float wu = whU[k], wl = whL[k];
            float4 wc = *(const float4*)(W_ch + (long)k * 256 + col);
            u[0] += wu * wc.x; u[1] += wu * wc.y; u[2] += wu * wc.z; u[3] += wu * wc.w;
            l[0] += wl * wc.x; l[1] += wl * wc.y; l[2] += wl * wc.z; l[3] += wl * wc.w;
        }
        unsigned* wrow = WP + (long)r * 256;
        st_u32(&wrow[col / 2],       __builtin_bit_cast(unsigned, __builtin_amdgcn_cvt_pkrtz(u[0], u[1])));
        st_u32(&wrow[col / 2 + 1],   __builtin_bit_cast(unsigned, __builtin_amdgcn_cvt_pkrtz(u[2], u[3])));
        st_u32(&wrow[128 + col / 2],     __builtin_bit_cast(unsigned, __builtin_amdgcn_cvt_pkrtz(l[0], l[1])));
        st_u32(&wrow[128 + col / 2 + 1], __builtin_bit_cast(unsigned, __builtin_amdgcn_cvt_pkrtz(l[2], l[3])));
        if ((tid & 63) == 0) {   // bias projections for this row
            float su = 0.f, sl = 0.f;
            for (int k = 0; k < 128; k++) { su += whU[k] * b_ch[k]; sl += whL[k] * b_ch[k]; }
            st_f32(&BU[r], su); st_f32(&BL[r], sl);
        }
    }
    drain_vmem();
    __syncthreads();
    if (tid == 0) st_flag(&InitF[bid * 16], BASE + 1u);

    // ---- wait ALL inits (covers every Hypproj row + all fused weights) ----
    wait_ge(&InitF[tid * 16], 1u);
    __syncthreads();

    // ---- load fused weight slice -> registers (f16x2), W_cc slice (fp32) ----
    h2 w[4][32];                  // 128 VGPRs
    #pragma unroll
    for (int a = 0; a < 4; a++) {
        const unsigned* src = WP + (long)(a * 256 + c * 32 + tq) * 256 + ks * 32;
        #pragma unroll
        for (int m = 0; m < 16; m++) {
            unsigned long long u2 = ld_u64((const unsigned long long*)(src + m * 2));
            w[a][2 * m]     = __builtin_bit_cast(h2, (unsigned)u2);
            w[a][2 * m + 1] = __builtin_bit_cast(h2, (unsigned)(u2 >> 32));
        }
    }
    float4 w3[8];                 // 32 VGPRs: W_cc row (c&3)*32+tq, K-seg ks*32..+32
    {
        const float* wr = W_cc + (long)((c & 3) * 32 + tq) * 256 + ks * 32;
        #pragma unroll
        for (int m = 0; m < 8; m++) w3[m] = *(const float4*)(wr + m * 4);
    }
    float bUv[4], bLv[4];
    #pragma unroll
    for (int a = 0; a < 4; a++) {
        bUv[a] = ld_f32(&BU[a * 256 + c * 32 + tl]);
        bLv[a] = ld_f32(&BL[a * 256 + c * 32 + tl]);
    }

    // ================= Wavefront: row i walks j = 0..31 =================
    #pragma unroll 1
    for (int j = 0; j < 32; j++) {
        const bool upok = (i > 0), lfok = (j > 0);
        const bool cok  = (c < 4) ? upok : lfok;
        const int  jl   = lfok ? (j - 1) : 0;

        // ---- prefetch Hypproj for elementwise (independent, overlaps the spin) ----
        float hyv[4];
        #pragma unroll
        for (int a = 0; a < 4; a++)
            hyv[a] = ld_f32(&Hypproj[j * 8192 + bb * 1024 + a * 256 + c * 32 + tl]);

        // ---- fine-grained dependency wait: 60 lanes, one per-wave flag each ----
        // lanes 0..31 : up blocks (i-1, cc=tid>>2), wave tid&3, target j+1
        // lanes 32..59: left siblings (i, cc != c), wave (tid-32)&3, target j
        {
            const unsigned* fp = nullptr;
            unsigned tgt = 0;
            if (upok && tid < 32) {
                fp = &WF[(((i - 1) * 8 + (tid >> 2)) * 4 + (tid & 3)) * 16];
                tgt = (unsigned)(j + 1);
            } else if (lfok && tid >= 32 && tid < 60) {
                int s = tid - 32;
                int cc = s >> 2;
                cc += (cc >= c) ? 1 : 0;          // skip self (own waves drained already)
                fp = &WF[((i * 8 + cc) * 4 + (s & 3)) * 16];
                tgt = (unsigned)j;
            }
            if (fp) wait_ge(fp, tgt);             // lanes exit individually; up & left concurrent
        }
        __syncthreads();

        // ---- one bulk load + LDS stage (no retries; flags imply visibility) ----
        const unsigned* HoUp = Ho + (size_t)(((i - 1) & 3) * 32 + j) * 1024;
        const unsigned* HoLf = Ho + (size_t)((i & 3) * 32 + jl) * 1024;
        const float*    CoS  = (c < 4)
            ? Co + (size_t)(((i - 1) & 3) * 32 + j) * 2048
            : Co + (size_t)((i & 3) * 32 + jl) * 2048;
        #pragma unroll
        for (int r = 0; r < 4; r++) {
            const int idx = r * 256 + tid;           // 0..1023
            const int b = idx >> 7, kk = idx & 127;  // f16 pair (2kk, 2kk+1)
            unsigned u = upok ? ld_flag(HoUp + b * 128 + kk) : 0u;
            unsigned l = lfok ? ld_flag(HoLf + b * 128 + kk) : 0u;
            float2 cv = cok ? ld_f32x2(CoS + b * 256 + 2 * kk) : make_float2(0.f, 0.f);
            hAB[b * 256 + kk]       = __builtin_bit_cast(h2, u);   // 0u == f16 pair (0,0)
            hAB[b * 256 + 128 + kk] = __builtin_bit_cast(h2, l);
            sCo[b * 256 + 2 * kk] = cv.x; sCo[b * 256 + 2 * kk + 1] = cv.y;
        }
        __syncthreads();

        // ---- fused gates GEMM (f16 dot2) + c-path (fp32) ----
        float acc[4][8], a3[8];
        #pragma unroll
        for (int a = 0; a < 4; a++)
            #pragma unroll
            for (int b = 0; b < 8; b++) acc[a][b] = 0.f;
        #pragma unroll
        for (int b = 0; b < 8; b++) a3[b] = 0.f;
        #pragma unroll
        for (int b = 0; b < 8; b++) {
            const h2*    hb = hAB + b * 256 + ks * 32;
            const float* cb = sCo + b * 256 + ks * 32;
            #pragma unroll
            for (int m4 = 0; m4 < 8; m4++) {
                uint4 hu = *(const uint4*)(hb + m4 * 4);
                h2 h0 = __builtin_bit_cast(h2, hu.x);
                h2 h1 = __builtin_bit_cast(h2, hu.y);
                h2 h2v = __builtin_bit_cast(h2, hu.z);
                h2 h3 = __builtin_bit_cast(h2, hu.w);
                #pragma unroll
                for (int a = 0; a < 4; a++) {
                    acc[a][b] = __builtin_amdgcn_fdot2(w[a][m4 * 4],     h0,  acc[a][b], false);
                    acc[a][b] = __builtin_amdgcn_fdot2(w[a][m4 * 4 + 1], h1,  acc[a][b], false);
                    acc[a][b] = __builtin_amdgcn_fdot2(w[a][m4 * 4 + 2], h2v, acc[a][b], false);
                    acc[a][b] = __builtin_amdgcn_fdot2(w[a][m4 * 4 + 3], h3,  acc[a][b], false);
                }
                float4 cv = *(const float4*)(cb + m4 * 4);
                a3[b] += w3[m4].x * cv.x + w3[m4].y * cv.y + w3[m4].z * cv.z + w3[m4].w * cv.w;
            }
        }
        #pragma unroll
        for (int a = 0; a < 4; a++)
            #pragma unroll
            for (int b = 0; b < 8; b++) red[tid * 33 + a * 8 + b] = acc[a][b];
        #pragma unroll
        for (int b = 0; b < 8; b++) red2[tid * 9 + b] = a3[b];
        __syncthreads();

        // ---- elementwise (block-local) + per-wave publish + per-wave flag ----
        {
            float g4[4];
            #pragma unroll
            for (int a = 0; a < 4; a++) {
                float s = 0.f;
                #pragma unroll
                for (int k = 0; k < 8; k++)
                    s += red[(k * 32 + tl) * 33 + a * 8 + bb];
                s += ppL[bb * 128 + a * 32 + tl] + hyv[a];
                if (upok) s += bUv[a];
                if (lfok) s += bLv[a];
                g4[a] = s;
            }
            float ci = 0.f;
            #pragma unroll
            for (int k = 0; k < 8; k++) ci += red2[(k * 32 + tl) * 9 + bb];
            if (cok) ci += b_cc[(c & 3) * 32 + tl];
            const float cnew = sigm(g4[1]) * ci + sigm(g4[0]) * tanh_fast(g4[2]);
            const float hnew = sigm(g4[3]) * tanh_fast(cnew);

            const int slot = (i & 3) * 32 + j;
            st_f32(&Co[(size_t)slot * 2048 + bb * 256 + c * 32 + tl], cnew);
            const float hOdd = __shfl_xor(hnew, 1);
            if ((tl & 1) == 0)
                st_u32(&Ho[(size_t)slot * 1024 + bb * 128 + c * 16 + (tl >> 1)],
                       __builtin_bit_cast(unsigned, pk_f16(hnew, hOdd)));
            if (i == 31 && j == 31)
                st_f32(&HoF[bb * 256 + c * 32 + tl], hnew);   // full-precision corner
        }
        // per-wave: drain own stores (wave-local vmcnt), then fire own flag.
        // No cross-wave barrier: consumers wait each wave's flag separately.
        drain_vmem();
        if ((tid & 63) == 0)
            st_flag(&WF[((i * 8 + c) * 4 + (tid >> 6)) * 16], BASE + (unsigned)(j + 1));
    }

    // ================= Final: condense ho(31,31) + MLP + softmax (bid 31) ==========
    if (bid == 31) {
        if (tid < 32)
            wait_ge(&WF[((31 * 8 + (tid >> 2)) * 4 + (tid & 3)) * 16], 32u);
        __syncthreads();
        #pragma unroll
        for (int r = 0; r < 8; r++)
            sCo[r * 256 + tid] = ld_f32(&HoF[r * 256 + tid]);
        __syncthreads();
        // condense: hcond[b][o] = b_ch[o] + W_ch[o,:] @ ho[b,:]
        #pragma unroll 1
        for (int q = 0; q < 4; q++) {
            const int oo = tid + q * 256;
            const int b = oo >> 7, o = oo & 127;
            float a = b_ch[o];
            const float* wr = W_ch + (long)o * 256;
            const float* x = sCo + b * 256;
            for (int k = 0; k < 256; k += 4) {
                float4 wv = *(const float4*)(wr + k);
                float4 xv = *(const float4*)(x + k);
                a += wv.x * xv.x + wv.y * xv.y + wv.z * xv.z + wv.w * xv.w;
            }
            ppL[b * 128 + o] = a;
        }
        __syncthreads();
        float* m1 = red;          // [8][128]
        float* m2 = red + 1024;   // [8][128]
        for (int idx = tid; idx < 1024; idx += 256) {
            int b = idx >> 7, o = idx & 127;
            float a = b1[o];
            const float* wr = W1 + o * 128; const float* x = ppL + b * 128;
            for (int k = 0; k < 128; k++) a += wr[k] * x[k];
            m1[idx] = fmaxf(a, 0.f);
        }
        __syncthreads();
        for (int idx = tid; idx < 1024; idx += 256) {
            int b = idx >> 7, o = idx & 127;
            float a = b2[o];
            const float* wr = W2 + o * 128; const float* x = m1 + b * 128;
            for (int k = 0; k < 128; k++) a += wr[k] * x[k];
            m2[idx] = fmaxf(a, 0.f);
        }
        __syncthreads();
        if (tid < 8) {
            const int b = tid;
            float lg[3];
            for (int cc = 0; cc < 3; cc++) {
                float a = b3[cc];
                const float* wr = W3 + cc * 128; const float* x = m2 + b * 128;
                for (int k = 0; k < 128; k++) a += wr[k] * x[k];
                lg[cc] = a;
            }
            float m = fmaxf(lg[0], fmaxf(lg[1], lg[2]));
            float e0 = expf(lg[0] - m), e1 = expf(lg[1] - m), e2 = expf(lg[2] - m);
            float s = e0 + e1 + e2;
            out[b * 3 + 0] = e0 / s;
            out[b * 3 + 1] = e1 / s;
            out[b * 3 + 2] = e2 / s;
        }
    }
}

extern "C" void kernel_launch(void* const* d_in, const int* in_sizes, int n_in,
                              void* d_out, int out_size, void* d_ws, size_t ws_size,
                              hipStream_t stream) {
    const int*   premise    = (const int*)d_in[0];
    const int*   hypothesis = (const int*)d_in[1];
    const float* emb        = (const float*)d_in[2];
    const float* W_ih       = (const float*)d_in[3];
    const float* b_ih       = (const float*)d_in[4];
    const float* W_hh       = (const float*)d_in[5];
    const float* b_hh       = (const float*)d_in[6];
    const float* W_ch       = (const float*)d_in[7];
    const float* b_ch       = (const float*)d_in[8];
    const float* W_cc       = (const float*)d_in[9];
    const float* b_cc       = (const float*)d_in[10];
    const float* W1         = (const float*)d_in[11];
    const float* b1         = (const float*)d_in[12];
    const float* W2         = (const float*)d_in[13];
    const float* b2         = (const float*)d_in[14];
    const float* W3         = (const float*)d_in[15];
    const float* b3         = (const float*)d_in[16];
    float* out = (float*)d_out;
    float* ws  = (float*)d_ws;

    (void)in_sizes; (void)n_in; (void)out_size; (void)ws_size;

    grid_lstm_kernel<<<dim3(256), dim3(256), 0, stream>>>(
        premise, hypothesis, emb, W_ih, b_ih, W_hh, b_hh,
        W_ch, b_ch, W_cc, b_cc, W1, b1, W2, b2, W3, b3, out, ws);
}